// Round 5
// baseline (356.402 us; speedup 1.0000x reference)
//
#include <hip/hip_runtime.h>
#include <cstdint>
#include <cstddef>

// Problem constants
#define DMODEL 1024
#define HEADS  16
#define DHEAD  64
#define BATCH  4
#define SEQ    2048
#define ROWS   (BATCH * SEQ)          // 8192
#define INV_DSCALE 0.3535533905932738f // 1 / 64^(1/4)

typedef float  f32x4  __attribute__((ext_vector_type(4)));
typedef __bf16 bf16x8 __attribute__((ext_vector_type(8)));
typedef unsigned short u16x8 __attribute__((ext_vector_type(8)));

__device__ __forceinline__ unsigned short f2bf(float x) {
    union { float f; unsigned u; } c; c.f = x;
    unsigned u = c.u;
    return (unsigned short)((u + 0x7fffu + ((u >> 16) & 1u)) >> 16);
}
__device__ __forceinline__ float bf2f(unsigned short h) {
    union { unsigned u; float f; } c; c.u = ((unsigned)h) << 16;
    return c.f;
}

// Pack two f32 -> packed 2x bf16 (RNE). gfx950 has v_cvt_pk_bf16_f32.
__device__ __forceinline__ unsigned cvt_pk_bf16(float a, float b) {
#if __has_builtin(__builtin_amdgcn_cvt_pk_bf16_f32)
    typedef __bf16 bf16x2_t __attribute__((ext_vector_type(2)));
    union { bf16x2_t v; unsigned u; } c;
    c.v = __builtin_amdgcn_cvt_pk_bf16_f32(a, b);
    return c.u;
#else
    return (unsigned)f2bf(a) | ((unsigned)f2bf(b) << 16);
#endif
}

__device__ __forceinline__ void load_g2l16(const unsigned short* g, unsigned short* l) {
    __builtin_amdgcn_global_load_lds(
        (const __attribute__((address_space(1))) unsigned int*)g,
        (__attribute__((address_space(3))) unsigned int*)l,
        16 /*bytes*/, 0 /*offset*/, 0 /*aux*/);
}

// ---------------------------------------------------------------------------
// Weight prep, one launch:
//  blocks [0,768):  pack Wq/Wk/Wv [h][m][d] fp32 -> Wt[n=h*64+d][k=m] bf16
//  blocks [768,1792): straight cast Wo (1M floats) -> bf16
__global__ __launch_bounds__(256) void prep_w(const float* __restrict__ W0,
                                              const float* __restrict__ W1,
                                              const float* __restrict__ W2,
                                              const float* __restrict__ Wo,
                                              unsigned short* __restrict__ T0,
                                              unsigned short* __restrict__ T1,
                                              unsigned short* __restrict__ T2,
                                              unsigned short* __restrict__ To) {
    __shared__ float tile[64][68];
    int blk = blockIdx.x;
    int t = threadIdx.x;
    if (blk < 768) {
        int w = blk >> 8, h = (blk >> 4) & 15, mb = blk & 15;
        const float* W = w == 0 ? W0 : (w == 1 ? W1 : W2);
        unsigned short* T = w == 0 ? T0 : (w == 1 ? T1 : T2);
        #pragma unroll
        for (int i = 0; i < 4; ++i) {
            int f = t + 256 * i;            // 0..1023
            int m = f >> 4, dg = (f & 15) * 4;
            *(float4*)&tile[m][dg] = *(const float4*)&W[((size_t)(h * 16 + mb) * 64 + m) * 64 + dg];
        }
        __syncthreads();
        #pragma unroll
        for (int i = 0; i < 2; ++i) {
            int f = t + 256 * i;            // 0..511
            int d = f >> 3, mg = f & 7;
            ushort4 a, b;
            a.x = f2bf(tile[mg * 8 + 0][d]); a.y = f2bf(tile[mg * 8 + 1][d]);
            a.z = f2bf(tile[mg * 8 + 2][d]); a.w = f2bf(tile[mg * 8 + 3][d]);
            b.x = f2bf(tile[mg * 8 + 4][d]); b.y = f2bf(tile[mg * 8 + 5][d]);
            b.z = f2bf(tile[mg * 8 + 6][d]); b.w = f2bf(tile[mg * 8 + 7][d]);
            unsigned short* dst = T + (size_t)(h * 64 + d) * DMODEL + mb * 64 + mg * 8;
            *(ushort4*)dst = a; *(ushort4*)(dst + 4) = b;
        }
    } else {
        int i = (blk - 768) * 256 + t;      // < 262144 float4 groups
        float4 v = ((const float4*)Wo)[i];
        ushort4 o;
        o.x = f2bf(v.x); o.y = f2bf(v.y); o.z = f2bf(v.z); o.w = f2bf(v.w);
        ((ushort4*)To)[i] = o;
    }
}

// ---------------------------------------------------------------------------
// Core: C[128x128 tile] = A[M,K] * B^T, B is [N,K] bf16 (K contiguous).
// BK=64, 4 waves each 64x64 via 4x4 of 16x16x32 MFMA (register-blocked per kh).
// XOR swizzle: LDS slot (row, s) holds global k-group s ^ (row&7).
// AF32: A is fp32 in global; convert to bf16 during LDS staging (fused cast).
// OBF16: store bf16 instead of fp32. sm: fused 64-wide head-group softmax.
template <bool OBF16, bool AF32>
__device__ __forceinline__ void gemm_core(const void* __restrict__ Av,
                                          const unsigned short* __restrict__ Bp,
                                          void* __restrict__ Cv,
                                          int K, int N, int bm0, int bn0, bool sm) {
    __shared__ unsigned short ldsA[128 * 64];   // 16 KB
    __shared__ unsigned short ldsB[128 * 64];   // 16 KB

    const int t    = threadIdx.x;
    const int lane = t & 63;
    const int wave = t >> 6;
    const int wm   = (wave & 1) * 64;
    const int wn   = (wave >> 1) * 64;
    const int fr   = lane & 15;
    const int quad = lane >> 4;

    const float*          A32 = (const float*)Av;
    const unsigned short* A16 = (const unsigned short*)Av;

    f32x4 acc[4][4] = {};

    // staging source addressing (global kg permuted by row&7; LDS dest linear)
    unsigned offA[4], offB[4];
    #pragma unroll
    for (int i = 0; i < 4; ++i) {
        int f = t + 256 * i, row = f >> 3, kg = (f & 7) ^ (row & 7);
        offA[i] = (unsigned)(bm0 + row) * K + kg * 8;
        offB[i] = (unsigned)(bn0 + row) * K + kg * 8;
    }

    for (int k0 = 0; k0 < K; k0 += 64) {
        if (AF32) {
            #pragma unroll
            for (int i = 0; i < 4; ++i) {
                const float* src = A32 + offA[i] + k0;
                float4 lo = *(const float4*)src;
                float4 hi = *(const float4*)(src + 4);
                uint4 pk;
                pk.x = cvt_pk_bf16(lo.x, lo.y);
                pk.y = cvt_pk_bf16(lo.z, lo.w);
                pk.z = cvt_pk_bf16(hi.x, hi.y);
                pk.w = cvt_pk_bf16(hi.z, hi.w);
                *(uint4*)&ldsA[(t + 256 * i) * 8] = pk;
            }
        } else {
            #pragma unroll
            for (int i = 0; i < 4; ++i)
                load_g2l16(A16 + offA[i] + k0, &ldsA[(t + 256 * i) * 8]);
        }
        #pragma unroll
        for (int i = 0; i < 4; ++i)
            load_g2l16(Bp + offB[i] + k0, &ldsB[(t + 256 * i) * 8]);
        asm volatile("s_waitcnt vmcnt(0)" ::: "memory");
        __syncthreads();

        #pragma unroll
        for (int kh = 0; kh < 2; ++kh) {
            bf16x8 af[4], bfr[4];
            #pragma unroll
            for (int i = 0; i < 4; ++i) {
                int row = wm + i * 16 + fr;
                int s = (kh * 4 + quad) ^ (row & 7);
                af[i] = *reinterpret_cast<const bf16x8*>(&ldsA[row * 64 + s * 8]);
            }
            #pragma unroll
            for (int j = 0; j < 4; ++j) {
                int row = wn + j * 16 + fr;
                int s = (kh * 4 + quad) ^ (row & 7);
                bfr[j] = *reinterpret_cast<const bf16x8*>(&ldsB[row * 64 + s * 8]);
            }
            #pragma unroll
            for (int i = 0; i < 4; ++i)
                #pragma unroll
                for (int j = 0; j < 4; ++j)
                    acc[i][j] = __builtin_amdgcn_mfma_f32_16x16x32_bf16(af[i], bfr[j], acc[i][j], 0, 0, 0);
        }

        __syncthreads();
    }

    // C/D layout: col = lane&15 (fr), row = quad*4 + reg
    #pragma unroll
    for (int i = 0; i < 4; ++i) {
        #pragma unroll
        for (int r = 0; r < 4; ++r) {
            float v[4];
            #pragma unroll
            for (int j = 0; j < 4; ++j) v[j] = acc[i][j][r];
            if (sm) {
                #pragma unroll
                for (int j = 0; j < 4; ++j) v[j] *= INV_DSCALE;
                float m = fmaxf(fmaxf(v[0], v[1]), fmaxf(v[2], v[3]));
                #pragma unroll
                for (int off = 8; off; off >>= 1) m = fmaxf(m, __shfl_xor(m, off, 16));
                float s = 0.f;
                #pragma unroll
                for (int j = 0; j < 4; ++j) { v[j] = __expf(v[j] - m); s += v[j]; }
                #pragma unroll
                for (int off = 8; off; off >>= 1) s += __shfl_xor(s, off, 16);
                float inv = 1.0f / s;
                #pragma unroll
                for (int j = 0; j < 4; ++j) v[j] *= inv;
            }
            int rr = bm0 + wm + i * 16 + quad * 4 + r;
            size_t base = (size_t)rr * N + bn0 + wn + fr;
            if (OBF16) {
                unsigned short* C = (unsigned short*)Cv;
                #pragma unroll
                for (int j = 0; j < 4; ++j) C[base + j * 16] = f2bf(v[j]);
            } else {
                float* C = (float*)Cv;
                #pragma unroll
                for (int j = 0; j < 4; ++j) C[base + j * 16] = v[j];
            }
        }
    }
}

// XCD-aware decode: flat%8 = XCD slot; each XCD owns an 8x8 patch of blocks
// (1024 A rows + full weight -> fits its 4 MB L2).
__device__ __forceinline__ void decode_blk(int flat, int& bm0, int& bn0) {
    int xcd = flat & 7, idx = flat >> 3;        // idx in [0,64)
    bm0 = (xcd * 8 + (idx >> 3)) * 128;
    bn0 = (idx & 7) * 128;
}

// Three projection GEMMs in one launch: blockIdx.y selects tensor; softmax for y<2.
__global__ __launch_bounds__(256, 3) void proj3(const float* __restrict__ xq,
                                                const float* __restrict__ xk,
                                                const float* __restrict__ xv,
                                                const unsigned short* __restrict__ wq,
                                                const unsigned short* __restrict__ wk,
                                                const unsigned short* __restrict__ wv,
                                                unsigned short* __restrict__ Qb,
                                                unsigned short* __restrict__ Kb,
                                                unsigned short* __restrict__ Vb) {
    int z = blockIdx.y;
    const float* A = z == 0 ? xq : (z == 1 ? xk : xv);
    const unsigned short* B = z == 0 ? wq : (z == 1 ? wk : wv);
    unsigned short* C = z == 0 ? Qb : (z == 1 ? Kb : Vb);
    int bm0, bn0;
    decode_blk(blockIdx.x, bm0, bn0);
    gemm_core<true, true>(A, B, C, DMODEL, DMODEL, bm0, bn0, z < 2);
}

// out = R (bf16 [8192,1024]) @ Wo^T -> fp32
__global__ __launch_bounds__(256, 3) void gemm_out(const unsigned short* __restrict__ R,
                                                   const unsigned short* __restrict__ Wo,
                                                   float* __restrict__ out) {
    int bm0, bn0;
    decode_blk(blockIdx.x, bm0, bn0);
    gemm_core<false, false>(R, Wo, out, DMODEL, DMODEL, bm0, bn0, false);
}

// ---------------------------------------------------------------------------
// P[chunk][bh][d][e] = sum over 128 s of Ks[b,s,h,d] * V[b,s,h,e]  (fp32 out,
// bf16 in). grid: bh*16 + chunk (1024 blocks), 32 KB LDS.
__global__ __launch_bounds__(256) void kv_outer(const unsigned short* __restrict__ Ks,
                                                const unsigned short* __restrict__ V,
                                                float* __restrict__ P) {
    __shared__ float sk[64][64];
    __shared__ float sv[64][64];
    int bh = blockIdx.x >> 4, chunk = blockIdx.x & 15;
    int b = bh >> 4, h = bh & 15;
    int t = threadIdx.x;
    int d = t & 63, eg = t >> 6;
    int e0 = eg * 16;
    float acc[16];
    #pragma unroll
    for (int j = 0; j < 16; ++j) acc[j] = 0.f;

    for (int sc = 0; sc < 2; ++sc) {
        int s0 = chunk * 128 + sc * 64;
        #pragma unroll
        for (int i = 0; i < 2; ++i) {
            int f = t + 256 * i;        // 0..511
            int r = f >> 3, c = (f & 7) * 8;
            size_t g = (size_t)(b * SEQ + s0 + r) * DMODEL + h * DHEAD + c;
            u16x8 kk = *(const u16x8*)&Ks[g];
            u16x8 vv = *(const u16x8*)&V[g];
            #pragma unroll
            for (int j = 0; j < 8; ++j) { sk[r][c + j] = bf2f(kk[j]); sv[r][c + j] = bf2f(vv[j]); }
        }
        __syncthreads();
        #pragma unroll 8
        for (int s = 0; s < 64; ++s) {
            float kd = sk[s][d];
            float4 v0 = *(const float4*)&sv[s][e0];
            float4 v1 = *(const float4*)&sv[s][e0 + 4];
            float4 v2 = *(const float4*)&sv[s][e0 + 8];
            float4 v3 = *(const float4*)&sv[s][e0 + 12];
            acc[0]  += kd * v0.x; acc[1]  += kd * v0.y; acc[2]  += kd * v0.z; acc[3]  += kd * v0.w;
            acc[4]  += kd * v1.x; acc[5]  += kd * v1.y; acc[6]  += kd * v1.z; acc[7]  += kd * v1.w;
            acc[8]  += kd * v2.x; acc[9]  += kd * v2.y; acc[10] += kd * v2.z; acc[11] += kd * v2.w;
            acc[12] += kd * v3.x; acc[13] += kd * v3.y; acc[14] += kd * v3.z; acc[15] += kd * v3.w;
        }
        __syncthreads();
    }
    float* Pp = P + ((size_t)chunk * 64 + bh) * 4096 + d * 64 + e0;
    #pragma unroll
    for (int j = 0; j < 16; j += 4)
        *(float4*)&Pp[j] = make_float4(acc[j], acc[j + 1], acc[j + 2], acc[j + 3]);
}

// A[idx] = sum over 16 chunks of P[chunk][idx], idx in [0, 64*4096)
__global__ __launch_bounds__(256) void reduce_A(const float* __restrict__ P,
                                                float* __restrict__ A) {
    int idx = blockIdx.x * 256 + threadIdx.x;   // 0 .. 262143
    float s = 0.f;
    #pragma unroll
    for (int c = 0; c < 16; ++c) s += P[(size_t)c * (64 * 4096) + idx];
    A[idx] = s;
}

// ---------------------------------------------------------------------------
// Bt[b,h,s,e] = sum_d Qs[b,s,h,d] * A[bh][d][e]; Qs bf16, A fp32; bf16 out in
// [b,h,s,e] flat order. grid: bh*32 + sb (sb covers 64 s rows)
__global__ __launch_bounds__(256) void qs_a(const unsigned short* __restrict__ Qs,
                                            const float* __restrict__ A,
                                            unsigned short* __restrict__ R) {
    __shared__ float sA[64][64];
    __shared__ float sQ[64][64];
    int bh = blockIdx.x >> 5, sb = blockIdx.x & 31;
    int b = bh >> 4, h = bh & 15;
    int t = threadIdx.x;
    #pragma unroll
    for (int i = 0; i < 4; ++i) {
        int f = t + 256 * i;            // float4 slot, 1024 total
        int r = f >> 4, c = (f & 15) * 4;
        *(float4*)&sA[r][c] = *(const float4*)&A[(size_t)bh * 4096 + (size_t)f * 4];
    }
    #pragma unroll
    for (int i = 0; i < 2; ++i) {
        int f = t + 256 * i;            // 0..511
        int r = f >> 3, c = (f & 7) * 8;
        u16x8 q = *(const u16x8*)&Qs[(size_t)(b * SEQ + sb * 64 + r) * DMODEL + h * DHEAD + c];
        #pragma unroll
        for (int j = 0; j < 8; ++j) sQ[r][c + j] = bf2f(q[j]);
    }
    __syncthreads();
    int lane = t & 63, w = t >> 6;
    float acc[16];
    #pragma unroll
    for (int r = 0; r < 16; ++r) acc[r] = 0.f;
    for (int d2 = 0; d2 < 64; d2 += 4) {
        float a0 = sA[d2][lane], a1 = sA[d2 + 1][lane];
        float a2 = sA[d2 + 2][lane], a3 = sA[d2 + 3][lane];
        #pragma unroll
        for (int r = 0; r < 16; ++r) {
            float4 q4 = *(const float4*)&sQ[w * 16 + r][d2];   // wave-broadcast
            acc[r] += q4.x * a0 + q4.y * a1 + q4.z * a2 + q4.w * a3;
        }
    }
    size_t base = (size_t)bh * (SEQ * DHEAD) + (size_t)(sb * 64 + w * 16) * DHEAD + lane;
    #pragma unroll
    for (int r = 0; r < 16; ++r) R[base + (size_t)r * DHEAD] = f2bf(acc[r]);
}

// ---------------------------------------------------------------------------
extern "C" void kernel_launch(void* const* d_in, const int* in_sizes, int n_in,
                              void* d_out, int out_size, void* d_ws, size_t ws_size,
                              hipStream_t stream) {
    const float* xq = (const float*)d_in[0];
    const float* xk = (const float*)d_in[1];
    const float* xv = (const float*)d_in[2];
    const float* Wq = (const float*)d_in[3];
    const float* Wk = (const float*)d_in[4];
    const float* Wv = (const float*)d_in[5];
    const float* Wo = (const float*)d_in[6];
    float* out = (float*)d_out;
    char* ws = (char*)d_ws;

    const size_t MB = 1ull << 20;
    unsigned short* wq_t = (unsigned short*)(ws + 0 * MB);    // 2 MB each
    unsigned short* wk_t = (unsigned short*)(ws + 2 * MB);
    unsigned short* wv_t = (unsigned short*)(ws + 4 * MB);
    unsigned short* wo_b = (unsigned short*)(ws + 6 * MB);    // 2 MB
    unsigned short* Qb = (unsigned short*)(ws + 8 * MB);      // bf16, 16 MB each
    unsigned short* Kb = (unsigned short*)(ws + 24 * MB);
    unsigned short* Vb = (unsigned short*)(ws + 40 * MB);
    float* Am = (float*)(ws + 56 * MB);                       // 1 MB
    unsigned short* R = (unsigned short*)(ws + 57 * MB);      // 16 MB
    float* P = (float*)(ws + 73 * MB);                        // 16 MB

    // weights -> bf16 (Wq/Wk/Wv packed N x K via LDS transpose; Wo straight)
    prep_w<<<1792, 256, 0, stream>>>(Wq, Wk, Wv, Wo, wq_t, wk_t, wv_t, wo_b);

    // projections with fused fp32->bf16 A-staging; softmax fused for Q,K; bf16 out
    proj3<<<dim3(512, 3), 256, 0, stream>>>(
        xq, xk, xv, wq_t, wk_t, wv_t, Qb, Kb, Vb);

    // A = softmax(K)^T V per (b,h): split-S partials then deterministic reduce
    kv_outer<<<BATCH * HEADS * 16, 256, 0, stream>>>(Kb, Vb, P);
    reduce_A<<<1024, 256, 0, stream>>>(P, Am);

    // Bt = softmax(Q) A -> bf16 R in [b,h,s,d] flat order (== reference reshape)
    qs_a<<<BATCH * HEADS * 32, 256, 0, stream>>>(Qb, Am, R);

    // out = R @ W_O^T  (fp32 out)
    gemm_out<<<512, 256, 0, stream>>>(R, wo_b, out);
}

// Round 6
// 268.967 us; speedup vs baseline: 1.3251x; 1.3251x over previous
//
#include <hip/hip_runtime.h>
#include <cstdint>
#include <cstddef>

// Problem constants
#define DMODEL 1024
#define HEADS  16
#define DHEAD  64
#define BATCH  4
#define SEQ    2048
#define ROWS   (BATCH * SEQ)          // 8192
#define INV_DSCALE 0.3535533905932738f // 1 / 64^(1/4)

typedef float  f32x4  __attribute__((ext_vector_type(4)));
typedef __bf16 bf16x8 __attribute__((ext_vector_type(8)));
typedef unsigned short u16x8 __attribute__((ext_vector_type(8)));

__device__ __forceinline__ unsigned short f2bf(float x) {
    union { float f; unsigned u; } c; c.f = x;
    unsigned u = c.u;
    return (unsigned short)((u + 0x7fffu + ((u >> 16) & 1u)) >> 16);
}

// Pack two f32 -> packed 2x bf16 (RNE).
__device__ __forceinline__ unsigned cvt_pk_bf16(float a, float b) {
#if __has_builtin(__builtin_amdgcn_cvt_pk_bf16_f32)
    typedef __bf16 bf16x2_t __attribute__((ext_vector_type(2)));
    union { bf16x2_t v; unsigned u; } c;
    c.v = __builtin_amdgcn_cvt_pk_bf16_f32(a, b);
    return c.u;
#else
    return (unsigned)f2bf(a) | ((unsigned)f2bf(b) << 16);
#endif
}

__device__ __forceinline__ void load_g2l16(const unsigned short* g, unsigned short* l) {
    __builtin_amdgcn_global_load_lds(
        (const __attribute__((address_space(1))) unsigned int*)g,
        (__attribute__((address_space(3))) unsigned int*)l,
        16 /*bytes*/, 0 /*offset*/, 0 /*aux*/);
}

// ---------------------------------------------------------------------------
// Weight prep: blocks [0,768) pack Wq/Wk/Wv -> [n=h*64+d][k=m] bf16;
// blocks [768,1792) straight-cast Wo.
__global__ __launch_bounds__(256) void prep_w(const float* __restrict__ W0,
                                              const float* __restrict__ W1,
                                              const float* __restrict__ W2,
                                              const float* __restrict__ Wo,
                                              unsigned short* __restrict__ T0,
                                              unsigned short* __restrict__ T1,
                                              unsigned short* __restrict__ T2,
                                              unsigned short* __restrict__ To) {
    __shared__ float tile[64][68];
    int blk = blockIdx.x;
    int t = threadIdx.x;
    if (blk < 768) {
        int w = blk >> 8, h = (blk >> 4) & 15, mb = blk & 15;
        const float* W = w == 0 ? W0 : (w == 1 ? W1 : W2);
        unsigned short* T = w == 0 ? T0 : (w == 1 ? T1 : T2);
        #pragma unroll
        for (int i = 0; i < 4; ++i) {
            int f = t + 256 * i;
            int m = f >> 4, dg = (f & 15) * 4;
            *(float4*)&tile[m][dg] = *(const float4*)&W[((size_t)(h * 16 + mb) * 64 + m) * 64 + dg];
        }
        __syncthreads();
        #pragma unroll
        for (int i = 0; i < 2; ++i) {
            int f = t + 256 * i;
            int d = f >> 3, mg = f & 7;
            ushort4 a, b;
            a.x = f2bf(tile[mg * 8 + 0][d]); a.y = f2bf(tile[mg * 8 + 1][d]);
            a.z = f2bf(tile[mg * 8 + 2][d]); a.w = f2bf(tile[mg * 8 + 3][d]);
            b.x = f2bf(tile[mg * 8 + 4][d]); b.y = f2bf(tile[mg * 8 + 5][d]);
            b.z = f2bf(tile[mg * 8 + 6][d]); b.w = f2bf(tile[mg * 8 + 7][d]);
            unsigned short* dst = T + (size_t)(h * 64 + d) * DMODEL + mb * 64 + mg * 8;
            *(ushort4*)dst = a; *(ushort4*)(dst + 4) = b;
        }
    } else {
        int i = (blk - 768) * 256 + t;
        float4 v = ((const float4*)Wo)[i];
        ushort4 o;
        o.x = f2bf(v.x); o.y = f2bf(v.y); o.z = f2bf(v.z); o.w = f2bf(v.w);
        ((ushort4*)To)[i] = o;
    }
}

// ---------------------------------------------------------------------------
// R4-proven GEMM tile: 64x128, BK=64, 4 waves each 32x64 (2x4 of 16x16x32).
// XOR swizzle: LDS slot (row, s) holds global k-group s ^ (row&7).
// AF32: A fp32 in global, converted to bf16 during staging.
// Computes acc[2][4]; epilogue is the caller's.
template <bool AF32>
__device__ __forceinline__ void gemm_tile(const void* __restrict__ Av,
                                          const unsigned short* __restrict__ Bp,
                                          int K, int bm0, int bn0,
                                          unsigned short* smem, f32x4 acc[2][4]) {
    unsigned short* ldsA = smem;            // 64*64 u16 = 8 KB
    unsigned short* ldsB = smem + 4096;     // 128*64 u16 = 16 KB

    const int t    = threadIdx.x;
    const int lane = t & 63;
    const int wave = t >> 6;
    const int wm   = (wave & 1) * 32;
    const int wn   = (wave >> 1) * 64;
    const int fr   = lane & 15;
    const int quad = lane >> 4;

    const float*          A32 = (const float*)Av;
    const unsigned short* A16 = (const unsigned short*)Av;

    unsigned offA[2], offB[4];
    #pragma unroll
    for (int i = 0; i < 2; ++i) {
        int f = t + 256 * i, row = f >> 3, kg = (f & 7) ^ (row & 7);
        offA[i] = (unsigned)(bm0 + row) * K + kg * 8;
    }
    #pragma unroll
    for (int i = 0; i < 4; ++i) {
        int f = t + 256 * i, row = f >> 3, kg = (f & 7) ^ (row & 7);
        offB[i] = (unsigned)(bn0 + row) * K + kg * 8;
    }

    for (int k0 = 0; k0 < K; k0 += 64) {
        if (AF32) {
            #pragma unroll
            for (int i = 0; i < 2; ++i) {
                const float* src = A32 + offA[i] + k0;
                float4 lo = *(const float4*)src;
                float4 hi = *(const float4*)(src + 4);
                uint4 pk;
                pk.x = cvt_pk_bf16(lo.x, lo.y);
                pk.y = cvt_pk_bf16(lo.z, lo.w);
                pk.z = cvt_pk_bf16(hi.x, hi.y);
                pk.w = cvt_pk_bf16(hi.z, hi.w);
                *(uint4*)&ldsA[(t + 256 * i) * 8] = pk;
            }
        } else {
            #pragma unroll
            for (int i = 0; i < 2; ++i)
                load_g2l16(A16 + offA[i] + k0, &ldsA[(t + 256 * i) * 8]);
        }
        #pragma unroll
        for (int i = 0; i < 4; ++i)
            load_g2l16(Bp + offB[i] + k0, &ldsB[(t + 256 * i) * 8]);
        asm volatile("s_waitcnt vmcnt(0)" ::: "memory");
        __syncthreads();

        bf16x8 af[2][2], bfr[4][2];
        #pragma unroll
        for (int i = 0; i < 2; ++i) {
            int row = wm + i * 16 + fr;
            #pragma unroll
            for (int kh = 0; kh < 2; ++kh) {
                int s = (kh * 4 + quad) ^ (row & 7);
                af[i][kh] = *reinterpret_cast<const bf16x8*>(&ldsA[row * 64 + s * 8]);
            }
        }
        #pragma unroll
        for (int j = 0; j < 4; ++j) {
            int row = wn + j * 16 + fr;
            #pragma unroll
            for (int kh = 0; kh < 2; ++kh) {
                int s = (kh * 4 + quad) ^ (row & 7);
                bfr[j][kh] = *reinterpret_cast<const bf16x8*>(&ldsB[row * 64 + s * 8]);
            }
        }
        #pragma unroll
        for (int kh = 0; kh < 2; ++kh)
            #pragma unroll
            for (int i = 0; i < 2; ++i)
                #pragma unroll
                for (int j = 0; j < 4; ++j)
                    acc[i][j] = __builtin_amdgcn_mfma_f32_16x16x32_bf16(af[i][kh], bfr[j][kh], acc[i][j], 0, 0, 0);

        __syncthreads();
    }
}

// Fused 64-wide head-group softmax over the wave's 4 j-frags (one head).
__device__ __forceinline__ void softmax4(float v[4]) {
    #pragma unroll
    for (int j = 0; j < 4; ++j) v[j] *= INV_DSCALE;
    float m = fmaxf(fmaxf(v[0], v[1]), fmaxf(v[2], v[3]));
    #pragma unroll
    for (int off = 8; off; off >>= 1) m = fmaxf(m, __shfl_xor(m, off, 16));
    float s = 0.f;
    #pragma unroll
    for (int j = 0; j < 4; ++j) { v[j] = __expf(v[j] - m); s += v[j]; }
    #pragma unroll
    for (int off = 8; off; off >>= 1) s += __shfl_xor(s, off, 16);
    float inv = 1.0f / s;
    #pragma unroll
    for (int j = 0; j < 4; ++j) v[j] *= inv;
}

// XCD-aware decode for 1024 blocks (128 m-blocks x 8 n-blocks of a 64x128 tile):
// flat%8 = XCD slot; each XCD owns a 16m x 8n patch (1024 A-rows -> its L2).
__device__ __forceinline__ void decode_blk(int flat, int& bm0, int& bn0) {
    int xcd = flat & 7, idx = flat >> 3;        // idx in [0,128)
    bm0 = (xcd * 16 + (idx >> 3)) * 64;
    bn0 = (idx & 7) * 128;
}

// ---------------------------------------------------------------------------
// Projections. z=0: Q -> softmax -> Qb [row][1024] bf16.
// z=1: K -> softmax -> TRANSPOSED Kt[bh][d][s] bf16 (via LDS transpose).
// z=2: V -> TRANSPOSED Vt[bh][e][s] bf16.
__global__ __launch_bounds__(256, 4) void proj3(const float* __restrict__ xq,
                                                const float* __restrict__ xk,
                                                const float* __restrict__ xv,
                                                const unsigned short* __restrict__ wq,
                                                const unsigned short* __restrict__ wk,
                                                const unsigned short* __restrict__ wv,
                                                unsigned short* __restrict__ Qb,
                                                unsigned short* __restrict__ Kt,
                                                unsigned short* __restrict__ Vt) {
    __shared__ unsigned short smem[12288];      // 24 KB: gemm staging, then Ct
    int z = blockIdx.y;
    const float* A = z == 0 ? xq : (z == 1 ? xk : xv);
    const unsigned short* B = z == 0 ? wq : (z == 1 ? wk : wv);
    int bm0, bn0;
    decode_blk(blockIdx.x, bm0, bn0);

    f32x4 acc[2][4] = {};
    gemm_tile<true>(A, B, DMODEL, bm0, bn0, smem, acc);

    const int t    = threadIdx.x;
    const int lane = t & 63;
    const int wave = t >> 6;
    const int wm   = (wave & 1) * 32;
    const int wn   = (wave >> 1) * 64;
    const int fr   = lane & 15;
    const int quad = lane >> 4;
    bool do_sm = (z < 2);

    if (z == 0) {
        #pragma unroll
        for (int i = 0; i < 2; ++i)
            #pragma unroll
            for (int r = 0; r < 4; ++r) {
                float v[4];
                #pragma unroll
                for (int j = 0; j < 4; ++j) v[j] = acc[i][j][r];
                softmax4(v);
                int rr = bm0 + wm + i * 16 + quad * 4 + r;
                size_t base = (size_t)rr * DMODEL + bn0 + wn + fr;
                #pragma unroll
                for (int j = 0; j < 4; ++j) Qb[base + j * 16] = f2bf(v[j]);
            }
    } else {
        // transpose epilogue: Ct[col][s_local], pitch 72 (2-way-free banks, 16B-aligned rows)
        unsigned short* Ct = smem;              // 128*72 u16 = 18 KB <= 24 KB
        #pragma unroll
        for (int i = 0; i < 2; ++i)
            #pragma unroll
            for (int r = 0; r < 4; ++r) {
                float v[4];
                #pragma unroll
                for (int j = 0; j < 4; ++j) v[j] = acc[i][j][r];
                if (do_sm) softmax4(v);
                int rr = wm + i * 16 + quad * 4 + r;          // s_local 0..63
                #pragma unroll
                for (int j = 0; j < 4; ++j) {
                    int cc = wn + j * 16 + fr;                // col 0..127
                    Ct[cc * 72 + rr] = f2bf(v[j]);
                }
            }
        __syncthreads();
        // coalesced-per-row copy out: thread t handles col c = t>>1, s-half (t&1)*32
        unsigned short* T = (z == 1) ? Kt : Vt;
        int c = t >> 1, sh = (t & 1) * 32;
        int col = bn0 + c, h = col >> 6, d = col & 63;
        int b = bm0 >> 11, s0 = bm0 & 2047;
        unsigned short* dst = T + (((size_t)(b * 16 + h) * 64 + d) << 11) + s0 + sh;
        const unsigned short* src = &Ct[c * 72 + sh];
        #pragma unroll
        for (int k = 0; k < 4; ++k)
            *(uint4*)(dst + k * 8) = *(const uint4*)(src + k * 8);
    }
}

// out = R (bf16 [8192,1024] flat) @ Wo^T -> fp32
__global__ __launch_bounds__(256, 4) void gemm_out(const unsigned short* __restrict__ R,
                                                   const unsigned short* __restrict__ Wo,
                                                   float* __restrict__ out) {
    __shared__ unsigned short smem[12288];
    int bm0, bn0;
    decode_blk(blockIdx.x, bm0, bn0);
    f32x4 acc[2][4] = {};
    gemm_tile<false>(R, Wo, DMODEL, bm0, bn0, smem, acc);

    const int t = threadIdx.x, lane = t & 63, wave = t >> 6;
    const int wm = (wave & 1) * 32, wn = (wave >> 1) * 64;
    const int fr = lane & 15, quad = lane >> 4;
    #pragma unroll
    for (int i = 0; i < 2; ++i)
        #pragma unroll
        for (int r = 0; r < 4; ++r) {
            int rr = bm0 + wm + i * 16 + quad * 4 + r;
            size_t base = (size_t)rr * DMODEL + bn0 + wn + fr;
            #pragma unroll
            for (int j = 0; j < 4; ++j) out[base + j * 16] = acc[i][j][r];
        }
}

// ---------------------------------------------------------------------------
// P[chunk][bh][e][d] = sum over 256 s of Vt[bh,e,s] * Kt[bh,d,s]  (MFMA).
// grid: bh*8 + chunk (512 blocks). At = softmax(K)^T V computed TRANSPOSED
// ([e][d]) so qs_mfma can use it as a B^T operand.
__global__ __launch_bounds__(256) void kv_mfma(const unsigned short* __restrict__ Vt,
                                               const unsigned short* __restrict__ Kt,
                                               float* __restrict__ P) {
    __shared__ unsigned short ldsV[64 * 64];    // 8 KB
    __shared__ unsigned short ldsK[64 * 64];    // 8 KB
    int bh = blockIdx.x >> 3, chunk = blockIdx.x & 7;
    int t = threadIdx.x, lane = t & 63, wave = t >> 6;
    int fr = lane & 15, quad = lane >> 4;

    unsigned offV[2], offK[2];
    #pragma unroll
    for (int i = 0; i < 2; ++i) {
        int f = t + 256 * i, row = f >> 3, kg = (f & 7) ^ (row & 7);
        unsigned o = ((unsigned)(bh * 64 + row) << 11) + chunk * 256 + kg * 8;
        offV[i] = o; offK[i] = o;
    }

    f32x4 acc[4] = {};
    for (int k0 = 0; k0 < 256; k0 += 64) {
        #pragma unroll
        for (int i = 0; i < 2; ++i)
            load_g2l16(Vt + offV[i] + k0, &ldsV[(t + 256 * i) * 8]);
        #pragma unroll
        for (int i = 0; i < 2; ++i)
            load_g2l16(Kt + offK[i] + k0, &ldsK[(t + 256 * i) * 8]);
        asm volatile("s_waitcnt vmcnt(0)" ::: "memory");
        __syncthreads();

        #pragma unroll
        for (int kh = 0; kh < 2; ++kh) {
            int rowA = wave * 16 + fr;
            int sA = (kh * 4 + quad) ^ (rowA & 7);
            bf16x8 av = *reinterpret_cast<const bf16x8*>(&ldsV[rowA * 64 + sA * 8]);
            #pragma unroll
            for (int j = 0; j < 4; ++j) {
                int rowB = j * 16 + fr;
                int sB = (kh * 4 + quad) ^ (rowB & 7);
                bf16x8 bv = *reinterpret_cast<const bf16x8*>(&ldsK[rowB * 64 + sB * 8]);
                acc[j] = __builtin_amdgcn_mfma_f32_16x16x32_bf16(av, bv, acc[j], 0, 0, 0);
            }
        }
        __syncthreads();
    }
    // C layout: e = wave*16 + quad*4 + r, d = j*16 + fr
    float* Pp = P + ((size_t)chunk * 64 + bh) * 4096;
    #pragma unroll
    for (int j = 0; j < 4; ++j)
        #pragma unroll
        for (int r = 0; r < 4; ++r)
            Pp[(wave * 16 + quad * 4 + r) * 64 + j * 16 + fr] = acc[j][r];
}

// At[idx] (bf16) = sum over 8 chunks of P[chunk][idx], idx in [0, 64*4096)
__global__ __launch_bounds__(256) void reduce_A(const float* __restrict__ P,
                                                unsigned short* __restrict__ At) {
    int idx = blockIdx.x * 256 + threadIdx.x;   // 0 .. 262143
    float s = 0.f;
    #pragma unroll
    for (int c = 0; c < 8; ++c) s += P[(size_t)c * (64 * 4096) + idx];
    At[idx] = f2bf(s);
}

// ---------------------------------------------------------------------------
// R[bh][s][e] = sum_d Qs[b,s,h*64+d] * At[bh][e][d]  (MFMA, K=64 single round).
// grid: bh*16 + sb (sb covers 128 s rows). Output bf16 flat [b,h,s,e].
__global__ __launch_bounds__(256, 4) void qs_mfma(const unsigned short* __restrict__ Qb,
                                                  const unsigned short* __restrict__ At,
                                                  unsigned short* __restrict__ R) {
    __shared__ unsigned short ldsQ[128 * 64];   // 16 KB
    __shared__ unsigned short ldsB[64 * 64];    // 8 KB
    int bh = blockIdx.x >> 4, sb = blockIdx.x & 15;
    int b = bh >> 4, h = bh & 15;
    int t = threadIdx.x, lane = t & 63, wave = t >> 6;
    int fr = lane & 15, quad = lane >> 4;
    int wm = wave * 32;

    #pragma unroll
    for (int i = 0; i < 4; ++i) {
        int f = t + 256 * i, row = f >> 3, kg = (f & 7) ^ (row & 7);
        const unsigned short* src = Qb + ((size_t)(b * SEQ + sb * 128 + row) << 10) + h * 64 + kg * 8;
        load_g2l16(src, &ldsQ[f * 8]);
    }
    #pragma unroll
    for (int i = 0; i < 2; ++i) {
        int f = t + 256 * i, row = f >> 3, kg = (f & 7) ^ (row & 7);
        load_g2l16(At + (unsigned)bh * 4096 + row * 64 + kg * 8, &ldsB[f * 8]);
    }
    asm volatile("s_waitcnt vmcnt(0)" ::: "memory");
    __syncthreads();

    f32x4 acc[2][4] = {};
    #pragma unroll
    for (int kh = 0; kh < 2; ++kh) {
        bf16x8 af[2], bfr[4];
        #pragma unroll
        for (int i = 0; i < 2; ++i) {
            int row = wm + i * 16 + fr;
            int s = (kh * 4 + quad) ^ (row & 7);
            af[i] = *reinterpret_cast<const bf16x8*>(&ldsQ[row * 64 + s * 8]);
        }
        #pragma unroll
        for (int j = 0; j < 4; ++j) {
            int row = j * 16 + fr;
            int s = (kh * 4 + quad) ^ (row & 7);
            bfr[j] = *reinterpret_cast<const bf16x8*>(&ldsB[row * 64 + s * 8]);
        }
        #pragma unroll
        for (int i = 0; i < 2; ++i)
            #pragma unroll
            for (int j = 0; j < 4; ++j)
                acc[i][j] = __builtin_amdgcn_mfma_f32_16x16x32_bf16(af[i], bfr[j], acc[i][j], 0, 0, 0);
    }

    // rr = s_local, cc = e; R flat [b,h,s,e]
    #pragma unroll
    for (int i = 0; i < 2; ++i)
        #pragma unroll
        for (int r = 0; r < 4; ++r) {
            int rr = wm + i * 16 + quad * 4 + r;
            size_t base = ((size_t)bh << 17) + (size_t)(sb * 128 + rr) * 64;
            #pragma unroll
            for (int j = 0; j < 4; ++j)
                R[base + j * 16 + fr] = f2bf(acc[i][j][r]);
        }
}

// ---------------------------------------------------------------------------
extern "C" void kernel_launch(void* const* d_in, const int* in_sizes, int n_in,
                              void* d_out, int out_size, void* d_ws, size_t ws_size,
                              hipStream_t stream) {
    const float* xq = (const float*)d_in[0];
    const float* xk = (const float*)d_in[1];
    const float* xv = (const float*)d_in[2];
    const float* Wq = (const float*)d_in[3];
    const float* Wk = (const float*)d_in[4];
    const float* Wv = (const float*)d_in[5];
    const float* Wo = (const float*)d_in[6];
    float* out = (float*)d_out;
    char* ws = (char*)d_ws;

    const size_t MB = 1ull << 20;
    unsigned short* wq_t = (unsigned short*)(ws + 0 * MB);    // 2 MB each
    unsigned short* wk_t = (unsigned short*)(ws + 2 * MB);
    unsigned short* wv_t = (unsigned short*)(ws + 4 * MB);
    unsigned short* wo_b = (unsigned short*)(ws + 6 * MB);    // 2 MB
    unsigned short* Qb = (unsigned short*)(ws + 8 * MB);      // 16 MB
    unsigned short* Kt = (unsigned short*)(ws + 24 * MB);     // 16 MB [bh][d][s]
    unsigned short* Vt = (unsigned short*)(ws + 40 * MB);     // 16 MB [bh][e][s]
    unsigned short* At = (unsigned short*)(ws + 56 * MB);     // 0.5 MB [bh][e][d]
    unsigned short* R  = (unsigned short*)(ws + 57 * MB);     // 16 MB
    float* P = (float*)(ws + 73 * MB);                        // 8 MB

    // weights -> bf16
    prep_w<<<1792, 256, 0, stream>>>(Wq, Wk, Wv, Wo, wq_t, wk_t, wv_t, wo_b);

    // projections (fused fp32->bf16 staging, fused softmax, K/V transposed out)
    proj3<<<dim3(1024, 3), 256, 0, stream>>>(xq, xk, xv, wq_t, wk_t, wv_t, Qb, Kt, Vt);

    // At = (softmax(K)^T V)^T per bh via MFMA, split-8 + deterministic reduce
    kv_mfma<<<BATCH * HEADS * 8, 256, 0, stream>>>(Vt, Kt, P);
    reduce_A<<<1024, 256, 0, stream>>>(P, At);

    // R = softmax(Q) A -> bf16, [b,h,s,e] flat (== reference view)
    qs_mfma<<<BATCH * HEADS * 16, 256, 0, stream>>>(Qb, At, R);

    // out = R @ Wo^T (fp32)
    gemm_out<<<1024, 256, 0, stream>>>(R, wo_b, out);
}